// Round 5
// baseline (394.869 us; speedup 1.0000x reference)
//
#include <hip/hip_runtime.h>
#include <hip/hip_bf16.h>

#define NN    100000
#define DF    64
#define NPB   32
#define NBLK  ((NN + NPB - 1) / NPB)   // 3125

typedef __bf16 bf16x8 __attribute__((ext_vector_type(8)));
typedef float  f32x4  __attribute__((ext_vector_type(4)));

// tanh-approx gelu: x * sigmoid(2u), u = 0.79788456*(x + 0.044715 x^3)
__device__ __forceinline__ float gelu_f(float x) {
    float u2 = x * (1.5957691216057308f + 0.07135481627f * x * x);
    float s  = __expf(-u2);
    return __fdividef(x, 1.0f + s);
}

__global__ __launch_bounds__(256, 6)
void it_fused(const float* __restrict__ y, const float* __restrict__ fy,
              const float* __restrict__ W0, const float* __restrict__ b0,
              const float* __restrict__ W1, const float* __restrict__ b1,
              const int* __restrict__ nbr, const int* __restrict__ splits,
              float* __restrict__ out)
{
    __shared__ int   splitsL[NPB + 1];
    __shared__ float yselfL[NPB][3];
    __shared__ float nodeacc[NPB][DF];                 // 8 KB
    __shared__ int   nsL[4][64];                       // packed nb*32+sg, 1 KB
    __shared__ __align__(16) __bf16 aggW[4][64][8];    // 4 KB
    __shared__ __align__(16) __bf16 hL[4][16][DF];     // 8 KB (single buffer per wave)

    const int t    = threadIdx.x;
    const int n0   = blockIdx.x * NPB;
    const int nloc = min(NPB, NN - n0);

    if (t <= NPB) splitsL[t] = splits[min(n0 + t, NN)];
    if (t < NPB) {
        const int node = min(n0 + t, NN - 1);
        yselfL[t][0] = y[node * 3 + 0];
        yselfL[t][1] = y[node * 3 + 1];
        yselfL[t][2] = y[node * 3 + 2];
    }
    for (int i = t; i < NPB * DF / 4; i += 256) ((float4*)nodeacc)[i] = make_float4(0, 0, 0, 0);
    __syncthreads();

    const int e_begin = splitsL[0];
    const int e_end   = splitsL[NPB];
    const int lane = t & 63;
    const int wv   = t >> 6;
    const int col  = lane & 15;   // MFMA m/n minor index
    const int kg   = lane >> 4;   // MFMA K-group

    // ---- weight B-fragments (register-resident) ----
    bf16x8 w0f[4];                // B[k=kg*8+j][n=nt*16+col], K padded 6->32 with zeros
    #pragma unroll
    for (int nt = 0; nt < 4; nt++)
        #pragma unroll
        for (int j = 0; j < 8; j++) {
            const int k = kg * 8 + j;
            const float v = W0[min(k, 5) * DF + nt * 16 + col];
            w0f[nt][j] = (k < 6) ? (__bf16)v : (__bf16)0.0f;
        }
    bf16x8 w1f[4][2];             // B[k=kf*32+kg*8+j][n=nt*16+col]
    float  b0r[4], b1r[4];
    #pragma unroll
    for (int nt = 0; nt < 4; nt++) {
        b0r[nt] = b0[nt * 16 + col];
        b1r[nt] = b1[nt * 16 + col];
        #pragma unroll
        for (int kf = 0; kf < 2; kf++)
            #pragma unroll
            for (int j = 0; j < 8; j++)
                w1f[nt][kf][j] = (__bf16)W1[(kf * 32 + kg * 8 + j) * DF + nt * 16 + col];
    }

    // ---- pipeline prologue: cold-load first batch's (nbr, y) ----
    const int efirst = e_begin + wv * 64 + lane;
    int   nb_cur = 0;
    float ya0 = 0.f, ya1 = 0.f, ya2 = 0.f;
    if (efirst < e_end) {
        nb_cur = nbr[efirst];
        ya0 = y[nb_cur * 3 + 0]; ya1 = y[nb_cur * 3 + 1]; ya2 = y[nb_cur * 3 + 2];
    }

    // ---- barrier-free main loop: each wave owns 64-edge batches, stride 256 ----
    for (int ebase = e_begin + wv * 64; ebase < e_end; ebase += 256) {
        const int e = ebase + lane;

        int sg = 0;
        #pragma unroll
        for (int step = 16; step >= 1; step >>= 1)
            if (splitsL[sg + step] <= e) sg += step;
        sg = min(sg, NPB - 1);

        nsL[wv][lane] = (nb_cur << 5) | sg;
        bf16x8 ag = {};
        ag[0] = (__bf16)ya0; ag[1] = (__bf16)ya1; ag[2] = (__bf16)ya2;
        ag[3] = (__bf16)yselfL[sg][0];
        ag[4] = (__bf16)yselfL[sg][1];
        ag[5] = (__bf16)yselfL[sg][2];
        *(bf16x8*)&aggW[wv][lane][0] = ag;

        // prefetch next batch's neighbor index (hides under groups 0-1)
        const int en = e + 256;
        int nb_nxt = 0;
        if (en < e_end) nb_nxt = nbr[en];

        auto group = [&](int g) {
            const int gb = g * 16;
            const int qi = gb + kg * 4;
            const int p0 = nsL[wv][qi + 0], p1 = nsL[wv][qi + 1],
                      p2 = nsL[wv][qi + 2], p3 = nsL[wv][qi + 3];
            const int s0 = p0 & 31, s1 = p1 & 31, s2 = p2 & 31, s3 = p3 & 31;

            // issue all fy gathers for this group FIRST -> latency hides under MFMA0/gelu/transpose
            const float* f0 = fy + (p0 >> 5) * DF;
            const float* f1 = fy + (p1 >> 5) * DF;
            const float* f2 = fy + (p2 >> 5) * DF;
            const float* f3 = fy + (p3 >> 5) * DF;
            float fv0[4], fv1[4], fv2[4], fv3[4];
            #pragma unroll
            for (int nt = 0; nt < 4; nt++) {
                const int c = nt * 16 + col;
                fv0[nt] = f0[c]; fv1[nt] = f1[c]; fv2[nt] = f2[c]; fv3[nt] = f3[c];
            }

            bf16x8 af0 = {};
            if (kg == 0) af0 = *(const bf16x8*)&aggW[wv][gb + col][0];

            // layer 0 (K=32, only k<6 nonzero)
            f32x4 acc0[4] = {};
            #pragma unroll
            for (int nt = 0; nt < 4; nt++)
                acc0[nt] = __builtin_amdgcn_mfma_f32_16x16x32_bf16(af0, w0f[nt], acc0[nt], 0, 0, 0);

            // gelu + bias, transpose edge<->feature via swizzled per-wave LDS
            // (same-wave DS ordering makes single-buffer reuse across groups safe)
            __bf16* const hw = &hL[wv][0][0];
            #pragma unroll
            for (int nt = 0; nt < 4; nt++)
                #pragma unroll
                for (int r = 0; r < 4; r++) {
                    const int row = kg * 4 + r;
                    const float h = gelu_f(acc0[nt][r] + b0r[nt]);
                    const int byteoff = row * 128 + ((((nt * 16 + col) * 2)) ^ ((row & 7) << 4));
                    *(__bf16*)((char*)hw + byteoff) = (__bf16)h;
                }
            bf16x8 af1[2];
            #pragma unroll
            for (int kf = 0; kf < 2; kf++) {
                const int byteoff = col * 128 + ((kf * 64 + kg * 16) ^ ((col & 7) << 4));
                af1[kf] = *(const bf16x8*)((const char*)hw + byteoff);
            }

            // layer 1 (fp32 accum)
            f32x4 acc[4] = {};
            #pragma unroll
            for (int nt = 0; nt < 4; nt++) {
                acc[nt] = __builtin_amdgcn_mfma_f32_16x16x32_bf16(af1[0], w1f[nt][0], acc[nt], 0, 0, 0);
                acc[nt] = __builtin_amdgcn_mfma_f32_16x16x32_bf16(af1[1], w1f[nt][1], acc[nt], 0, 0, 0);
            }

            // gate by prefetched f_y values, segmented-reduce into LDS node accumulators
            const int rem = e_end - (ebase + qi);
            #pragma unroll
            for (int nt = 0; nt < 4; nt++) {
                const int   c  = nt * 16 + col;
                const float bb = b1r[nt];
                float v0 = (0 < rem) ? (acc[nt][0] + bb) * fv0[nt] : 0.0f;
                float v1 = (1 < rem) ? (acc[nt][1] + bb) * fv1[nt] : 0.0f;
                float v2 = (2 < rem) ? (acc[nt][2] + bb) * fv2[nt] : 0.0f;
                float v3 = (3 < rem) ? (acc[nt][3] + bb) * fv3[nt] : 0.0f;
                if (s0 == s3) {   // monotone seg -> all four equal: merged single atomic
                    unsafeAtomicAdd(&nodeacc[s0][c], ((v0 + v1) + (v2 + v3)));
                } else {
                    unsafeAtomicAdd(&nodeacc[s0][c], v0);
                    unsafeAtomicAdd(&nodeacc[s1][c], v1);
                    unsafeAtomicAdd(&nodeacc[s2][c], v2);
                    unsafeAtomicAdd(&nodeacc[s3][c], v3);
                }
            }
        };

        group(0); group(1);

        // mid-iter: gather next batch's y (nb_nxt landed under groups 0-1;
        // this gather's latency hides under groups 2-3)
        ya0 = ya1 = ya2 = 0.f;
        if (en < e_end) {
            ya0 = y[nb_nxt * 3 + 0]; ya1 = y[nb_nxt * 3 + 1]; ya2 = y[nb_nxt * 3 + 2];
        }
        nb_cur = nb_nxt;

        group(2); group(3);
    }

    __syncthreads();

    // ---- Epilogue: mean and store (each node owned by exactly this block) ----
    for (int i = t; i < nloc * (DF / 4); i += 256) {
        const int node = i >> 4;
        const int cnt  = splitsL[node + 1] - splitsL[node];
        const float inv = (cnt > 0) ? __fdividef(1.0f, (float)cnt) : 0.0f;
        float4 v = ((const float4*)nodeacc)[i];
        v.x *= inv; v.y *= inv; v.z *= inv; v.w *= inv;
        ((float4*)out)[n0 * (DF / 4) + i] = v;
    }
}

extern "C" void kernel_launch(void* const* d_in, const int* in_sizes, int n_in,
                              void* d_out, int out_size, void* d_ws, size_t ws_size,
                              hipStream_t stream) {
    const float* y   = (const float*)d_in[0];
    const float* fyv = (const float*)d_in[1];
    const float* W0  = (const float*)d_in[2];
    const float* b0  = (const float*)d_in[3];
    const float* W1  = (const float*)d_in[4];
    const float* b1  = (const float*)d_in[5];
    const int*   nb  = (const int*)d_in[6];   // harness delivers integer inputs as int32
    const int*   sp  = (const int*)d_in[7];
    it_fused<<<NBLK, 256, 0, stream>>>(y, fyv, W0, b0, W1, b1, nb, sp, (float*)d_out);
}

// Round 6
// 291.945 us; speedup vs baseline: 1.3525x; 1.3525x over previous
//
#include <hip/hip_runtime.h>
#include <hip/hip_bf16.h>

#define NN    100000
#define DF    64
#define NPB   32
#define NBLK  ((NN + NPB - 1) / NPB)   // 3125

typedef __bf16 bf16x8 __attribute__((ext_vector_type(8)));
typedef float  f32x4  __attribute__((ext_vector_type(4)));

// tanh-approx gelu: x * sigmoid(2u), u = 0.79788456*(x + 0.044715 x^3)
__device__ __forceinline__ float gelu_f(float x) {
    float u2 = x * (1.5957691216057308f + 0.07135481627f * x * x);
    float s  = __expf(-u2);
    return __fdividef(x, 1.0f + s);
}

__global__ __launch_bounds__(256, 4)
void it_fused(const float* __restrict__ y, const float* __restrict__ fy,
              const float* __restrict__ W0, const float* __restrict__ b0,
              const float* __restrict__ W1, const float* __restrict__ b1,
              const int* __restrict__ nbr, const int* __restrict__ splits,
              float* __restrict__ out)
{
    __shared__ int   splitsL[NPB + 1];
    __shared__ float yselfL[NPB][3];
    __shared__ float nodeacc[NPB][DF];                 // 8 KB
    __shared__ int   nsL[4][64];                       // packed nb*32+sg, 1 KB
    __shared__ __align__(16) __bf16 aggW[4][64][8];    // 4 KB
    __shared__ __align__(16) __bf16 hL[4][16][DF];     // 8 KB (single buffer per wave)

    const int t    = threadIdx.x;
    const int n0   = blockIdx.x * NPB;
    const int nloc = min(NPB, NN - n0);

    if (t <= NPB) splitsL[t] = splits[min(n0 + t, NN)];
    if (t < NPB) {
        const int node = min(n0 + t, NN - 1);
        yselfL[t][0] = y[node * 3 + 0];
        yselfL[t][1] = y[node * 3 + 1];
        yselfL[t][2] = y[node * 3 + 2];
    }
    for (int i = t; i < NPB * DF / 4; i += 256) ((float4*)nodeacc)[i] = make_float4(0, 0, 0, 0);
    __syncthreads();

    const int e_begin = splitsL[0];
    const int e_end   = splitsL[NPB];
    const int lane = t & 63;
    const int wv   = t >> 6;
    const int col  = lane & 15;   // MFMA m/n minor index
    const int kg   = lane >> 4;   // MFMA K-group

    // ---- weight B-fragments (register-resident) ----
    bf16x8 w0f[4];                // B[k=kg*8+j][n=nt*16+col], K padded 6->32 with zeros
    #pragma unroll
    for (int nt = 0; nt < 4; nt++)
        #pragma unroll
        for (int j = 0; j < 8; j++) {
            const int k = kg * 8 + j;
            const float v = W0[min(k, 5) * DF + nt * 16 + col];
            w0f[nt][j] = (k < 6) ? (__bf16)v : (__bf16)0.0f;
        }
    bf16x8 w1f[4][2];             // B[k=kf*32+kg*8+j][n=nt*16+col]
    float  b0r[4], b1r[4];
    #pragma unroll
    for (int nt = 0; nt < 4; nt++) {
        b0r[nt] = b0[nt * 16 + col];
        b1r[nt] = b1[nt * 16 + col];
        #pragma unroll
        for (int kf = 0; kf < 2; kf++)
            #pragma unroll
            for (int j = 0; j < 8; j++)
                w1f[nt][kf][j] = (__bf16)W1[(kf * 32 + kg * 8 + j) * DF + nt * 16 + col];
    }

    // ---- pipeline prologue: cold-load first batch's (nbr, y) ----
    const int efirst = e_begin + wv * 64 + lane;
    int   nb_cur = 0;
    float ya0 = 0.f, ya1 = 0.f, ya2 = 0.f;
    if (efirst < e_end) {
        nb_cur = nbr[efirst];
        ya0 = y[nb_cur * 3 + 0]; ya1 = y[nb_cur * 3 + 1]; ya2 = y[nb_cur * 3 + 2];
    }

    // ---- barrier-free main loop: each wave owns 64-edge batches, stride 256 ----
    for (int ebase = e_begin + wv * 64; ebase < e_end; ebase += 256) {
        const int e = ebase + lane;

        int sg = 0;
        #pragma unroll
        for (int step = 16; step >= 1; step >>= 1)
            if (splitsL[sg + step] <= e) sg += step;
        sg = min(sg, NPB - 1);

        nsL[wv][lane] = (nb_cur << 5) | sg;
        bf16x8 ag = {};
        ag[0] = (__bf16)ya0; ag[1] = (__bf16)ya1; ag[2] = (__bf16)ya2;
        ag[3] = (__bf16)yselfL[sg][0];
        ag[4] = (__bf16)yselfL[sg][1];
        ag[5] = (__bf16)yselfL[sg][2];
        *(bf16x8*)&aggW[wv][lane][0] = ag;

        // prefetch next batch's neighbor index (hides under groups 0-1)
        const int en = e + 256;
        int nb_nxt = 0;
        if (en < e_end) nb_nxt = nbr[en];

        auto group = [&](int g) {
            const int gb = g * 16;
            const int qi = gb + kg * 4;
            const int p0 = nsL[wv][qi + 0], p1 = nsL[wv][qi + 1],
                      p2 = nsL[wv][qi + 2], p3 = nsL[wv][qi + 3];
            const int s0 = p0 & 31, s1 = p1 & 31, s2 = p2 & 31, s3 = p3 & 31;

            bf16x8 af0 = {};
            if (kg == 0) af0 = *(const bf16x8*)&aggW[wv][gb + col][0];

            // layer 0 (K=32, only k<6 nonzero)
            f32x4 acc0[4] = {};
            #pragma unroll
            for (int nt = 0; nt < 4; nt++)
                acc0[nt] = __builtin_amdgcn_mfma_f32_16x16x32_bf16(af0, w0f[nt], acc0[nt], 0, 0, 0);

            // gelu + bias, transpose edge<->feature via swizzled per-wave LDS
            // (same-wave DS ordering makes single-buffer reuse across groups safe)
            __bf16* const hw = &hL[wv][0][0];
            #pragma unroll
            for (int nt = 0; nt < 4; nt++)
                #pragma unroll
                for (int r = 0; r < 4; r++) {
                    const int row = kg * 4 + r;
                    const float h = gelu_f(acc0[nt][r] + b0r[nt]);
                    const int byteoff = row * 128 + ((((nt * 16 + col) * 2)) ^ ((row & 7) << 4));
                    *(__bf16*)((char*)hw + byteoff) = (__bf16)h;
                }
            bf16x8 af1[2];
            #pragma unroll
            for (int kf = 0; kf < 2; kf++) {
                const int byteoff = col * 128 + ((kf * 64 + kg * 16) ^ ((col & 7) << 4));
                af1[kf] = *(const bf16x8*)((const char*)hw + byteoff);
            }

            // layer 1 (fp32 accum)
            f32x4 acc[4] = {};
            #pragma unroll
            for (int nt = 0; nt < 4; nt++) {
                acc[nt] = __builtin_amdgcn_mfma_f32_16x16x32_bf16(af1[0], w1f[nt][0], acc[nt], 0, 0, 0);
                acc[nt] = __builtin_amdgcn_mfma_f32_16x16x32_bf16(af1[1], w1f[nt][1], acc[nt], 0, 0, 0);
            }

            // gate by f_y[nbr], segmented-reduce into LDS node accumulators
            const float* f0 = fy + (p0 >> 5) * DF;
            const float* f1 = fy + (p1 >> 5) * DF;
            const float* f2 = fy + (p2 >> 5) * DF;
            const float* f3 = fy + (p3 >> 5) * DF;
            const int rem = e_end - (ebase + qi);
            #pragma unroll
            for (int nt = 0; nt < 4; nt++) {
                const int   c  = nt * 16 + col;
                const float bb = b1r[nt];
                float v0 = (0 < rem) ? (acc[nt][0] + bb) * f0[c] : 0.0f;
                float v1 = (1 < rem) ? (acc[nt][1] + bb) * f1[c] : 0.0f;
                float v2 = (2 < rem) ? (acc[nt][2] + bb) * f2[c] : 0.0f;
                float v3 = (3 < rem) ? (acc[nt][3] + bb) * f3[c] : 0.0f;
                if (s0 == s3) {   // monotone seg -> all four equal: merged single atomic
                    unsafeAtomicAdd(&nodeacc[s0][c], ((v0 + v1) + (v2 + v3)));
                } else {
                    unsafeAtomicAdd(&nodeacc[s0][c], v0);
                    unsafeAtomicAdd(&nodeacc[s1][c], v1);
                    unsafeAtomicAdd(&nodeacc[s2][c], v2);
                    unsafeAtomicAdd(&nodeacc[s3][c], v3);
                }
            }
        };

        group(0); group(1);

        // mid-iter: gather next batch's y (nb_nxt landed under groups 0-1;
        // this gather's latency hides under groups 2-3)
        ya0 = ya1 = ya2 = 0.f;
        if (en < e_end) {
            ya0 = y[nb_nxt * 3 + 0]; ya1 = y[nb_nxt * 3 + 1]; ya2 = y[nb_nxt * 3 + 2];
        }
        nb_cur = nb_nxt;

        group(2); group(3);
    }

    __syncthreads();

    // ---- Epilogue: mean and store (each node owned by exactly this block) ----
    for (int i = t; i < nloc * (DF / 4); i += 256) {
        const int node = i >> 4;
        const int cnt  = splitsL[node + 1] - splitsL[node];
        const float inv = (cnt > 0) ? __fdividef(1.0f, (float)cnt) : 0.0f;
        float4 v = ((const float4*)nodeacc)[i];
        v.x *= inv; v.y *= inv; v.z *= inv; v.w *= inv;
        ((float4*)out)[n0 * (DF / 4) + i] = v;
    }
}

extern "C" void kernel_launch(void* const* d_in, const int* in_sizes, int n_in,
                              void* d_out, int out_size, void* d_ws, size_t ws_size,
                              hipStream_t stream) {
    const float* y   = (const float*)d_in[0];
    const float* fyv = (const float*)d_in[1];
    const float* W0  = (const float*)d_in[2];
    const float* b0  = (const float*)d_in[3];
    const float* W1  = (const float*)d_in[4];
    const float* b1  = (const float*)d_in[5];
    const int*   nb  = (const int*)d_in[6];   // harness delivers integer inputs as int32
    const int*   sp  = (const int*)d_in[7];
    it_fused<<<NBLK, 256, 0, stream>>>(y, fyv, W0, b0, W1, b1, nb, sp, (float*)d_out);
}

// Round 7
// 250.391 us; speedup vs baseline: 1.5770x; 1.1660x over previous
//
#include <hip/hip_runtime.h>
#include <hip/hip_bf16.h>

#define NN    100000
#define DF    64
#define NPB   32
#define NBLK  ((NN + NPB - 1) / NPB)   // 3125

typedef __bf16 bf16x8 __attribute__((ext_vector_type(8)));
typedef float  f32x4  __attribute__((ext_vector_type(4)));

// tanh-approx gelu: x * sigmoid(2u), u = 0.79788456*(x + 0.044715 x^3)
__device__ __forceinline__ float gelu_f(float x) {
    float u2 = x * (1.5957691216057308f + 0.07135481627f * x * x);
    float s  = __expf(-u2);
    return __fdividef(x, 1.0f + s);
}

__device__ __forceinline__ unsigned cvt_pk_bf16(float lo, float hi) {
    unsigned r;
    asm("v_cvt_pk_bf16_f32 %0, %1, %2" : "=v"(r) : "v"(lo), "v"(hi));
    return r;
}

__global__ __launch_bounds__(256, 4)
void it_fused(const float* __restrict__ y, const float* __restrict__ fy,
              const float* __restrict__ W0, const float* __restrict__ b0,
              const float* __restrict__ W1, const float* __restrict__ b1,
              const int* __restrict__ nbr, const int* __restrict__ splits,
              float* __restrict__ out)
{
    __shared__ int   splitsL[NPB + 1];
    __shared__ float yselfL[NPB][3];
    __shared__ float nodeacc[NPB][DF];                       // 8 KB
    __shared__ __align__(16) int nsL[4][64];                 // packed nb*32+sg, 1 KB
    __shared__ __align__(16) __bf16 aggW[4][64][8];          // 4 KB
    __shared__ __align__(16) __bf16 hL[4][16][DF];           // 8 KB h0 transpose buf

    const int t    = threadIdx.x;
    const int n0   = blockIdx.x * NPB;
    const int nloc = min(NPB, NN - n0);

    if (t <= NPB) splitsL[t] = splits[min(n0 + t, NN)];
    if (t < NPB) {
        const int node = min(n0 + t, NN - 1);
        yselfL[t][0] = y[node * 3 + 0];
        yselfL[t][1] = y[node * 3 + 1];
        yselfL[t][2] = y[node * 3 + 2];
    }
    for (int i = t; i < NPB * DF / 4; i += 256) ((float4*)nodeacc)[i] = make_float4(0, 0, 0, 0);
    __syncthreads();

    const int e_begin = splitsL[0];
    const int e_end   = splitsL[NPB];
    const int lane = t & 63;
    const int wv   = t >> 6;
    const int col  = lane & 15;   // MFMA m/n minor index
    const int kg   = lane >> 4;   // MFMA K-group

    // ---- weight fragments (register-resident) ----
    // Layer 0 (used as MFMA *A* operand, swapped): A[m=feat nt*16+col][k=kg*8+j]
    // = W0ext[k][nt*16+col]; row 6 = b0 (bias via agg[6]=1), rows 7..31 = 0.
    bf16x8 w0f[4];
    #pragma unroll
    for (int nt = 0; nt < 4; nt++)
        #pragma unroll
        for (int j = 0; j < 8; j++) {
            const int k = kg * 8 + j;
            float v = 0.0f;
            if (k < 6)       v = W0[k * DF + nt * 16 + col];
            else if (k == 6) v = b0[nt * 16 + col];
            w0f[nt][j] = (__bf16)v;
        }
    // Layer 1 B-fragments with COLUMN PERMUTATION c = col*4 + nt:
    // B[k=kf*32+kg*8+j][n-tile nt, n-minor col] = W1[k][col*4+nt]
    bf16x8 w1f[4][2];
    float  b1r[4];
    #pragma unroll
    for (int nt = 0; nt < 4; nt++) {
        b1r[nt] = b1[col * 4 + nt];
        #pragma unroll
        for (int kf = 0; kf < 2; kf++)
            #pragma unroll
            for (int j = 0; j < 8; j++)
                w1f[nt][kf][j] = (__bf16)W1[(kf * 32 + kg * 8 + j) * DF + col * 4 + nt];
    }

    // ---- pipeline prologue: cold-load first batch's (nbr, y) ----
    const int efirst = e_begin + wv * 64 + lane;
    int   nb_cur = 0;
    float ya0 = 0.f, ya1 = 0.f, ya2 = 0.f;
    if (efirst < e_end) {
        nb_cur = nbr[efirst];
        ya0 = y[nb_cur * 3 + 0]; ya1 = y[nb_cur * 3 + 1]; ya2 = y[nb_cur * 3 + 2];
    }

    __bf16* const hw = &hL[wv][0][0];
    const int swz = (col & 7) << 4;

    // ---- barrier-free main loop: each wave owns 64-edge batches, stride 256 ----
    for (int ebase = e_begin + wv * 64; ebase < e_end; ebase += 256) {
        const int e = ebase + lane;

        int sg = 0;
        #pragma unroll
        for (int step = 16; step >= 1; step >>= 1)
            if (splitsL[sg + step] <= e) sg += step;
        sg = min(sg, NPB - 1);

        nsL[wv][lane] = (nb_cur << 5) | sg;
        bf16x8 ag = {};
        if (e < e_end) {
            ag[0] = (__bf16)ya0; ag[1] = (__bf16)ya1; ag[2] = (__bf16)ya2;
            ag[3] = (__bf16)yselfL[sg][0];
            ag[4] = (__bf16)yselfL[sg][1];
            ag[5] = (__bf16)yselfL[sg][2];
            ag[6] = (__bf16)1.0f;            // bias slot (W0ext row 6 = b0)
        }
        *(bf16x8*)&aggW[wv][lane][0] = ag;

        // prefetch next batch's neighbor index (hides under groups 0-1)
        const int en = e + 256;
        int nb_nxt = 0;
        if (en < e_end) nb_nxt = nbr[en];

        auto group = [&](int g) {
            const int gb = g * 16;
            const int qi = gb + kg * 4;
            const int4 q = *(const int4*)&nsL[wv][qi];

            bf16x8 af0 = {};
            if (kg == 0) af0 = *(const bf16x8*)&aggW[wv][gb + col][0];

            // layer 0 SWAPPED: D0 = W0ext^T * agg -> lane holds h0^T:
            // feature nt*16+kg*4+r, edge = col (bias included via k=6)
            f32x4 acc0[4] = {};
            #pragma unroll
            for (int nt = 0; nt < 4; nt++)
                acc0[nt] = __builtin_amdgcn_mfma_f32_16x16x32_bf16(w0f[nt], af0, acc0[nt], 0, 0, 0);

            // gelu + pack pairs + 4x ds_write_b64 into hL[edge=col][feature] (swizzled)
            #pragma unroll
            for (int nt = 0; nt < 4; nt++) {
                const unsigned p0 = cvt_pk_bf16(gelu_f(acc0[nt][0]), gelu_f(acc0[nt][1]));
                const unsigned p1 = cvt_pk_bf16(gelu_f(acc0[nt][2]), gelu_f(acc0[nt][3]));
                const int off = col * 128 + ((nt * 32 + kg * 8) ^ swz);
                *(int2*)((char*)hw + off) = make_int2((int)p0, (int)p1);
            }
            // read A-fragments for layer 1: edge=col, k = kf*32+kg*8+j
            bf16x8 af1[2];
            #pragma unroll
            for (int kf = 0; kf < 2; kf++) {
                const int off = col * 128 + ((kf * 64 + kg * 16) ^ swz);
                af1[kf] = *(const bf16x8*)((const char*)hw + off);
            }

            // layer 1 (fp32 accum): D1[edge=kg*4+r][c = col*4+nt]
            f32x4 acc[4] = {};
            #pragma unroll
            for (int nt = 0; nt < 4; nt++) {
                acc[nt] = __builtin_amdgcn_mfma_f32_16x16x32_bf16(af1[0], w1f[nt][0], acc[nt], 0, 0, 0);
                acc[nt] = __builtin_amdgcn_mfma_f32_16x16x32_bf16(af1[1], w1f[nt][1], acc[nt], 0, 0, 0);
            }

            // fy gather: ONE row per quad-edge, 16B vector load (cols col*4..col*4+3)
            const int s0 = q.x & 31, s1 = q.y & 31, s2 = q.z & 31, s3 = q.w & 31;
            const float4 fv0 = *(const float4*)(fy + (q.x >> 5) * DF + col * 4);
            const float4 fv1 = *(const float4*)(fy + (q.y >> 5) * DF + col * 4);
            const float4 fv2 = *(const float4*)(fy + (q.z >> 5) * DF + col * 4);
            const float4 fv3 = *(const float4*)(fy + (q.w >> 5) * DF + col * 4);

            const int rem = e_end - (ebase + qi);   // edge r valid iff r < rem
            #pragma unroll
            for (int nt = 0; nt < 4; nt++) {
                const int   c  = col * 4 + nt;
                const float bb = b1r[nt];
                float v0 = (0 < rem) ? (acc[nt][0] + bb) * ((const float*)&fv0)[nt] : 0.0f;
                float v1 = (1 < rem) ? (acc[nt][1] + bb) * ((const float*)&fv1)[nt] : 0.0f;
                float v2 = (2 < rem) ? (acc[nt][2] + bb) * ((const float*)&fv2)[nt] : 0.0f;
                float v3 = (3 < rem) ? (acc[nt][3] + bb) * ((const float*)&fv3)[nt] : 0.0f;
                if (s0 == s3) {   // monotone seg -> all four equal: merged single atomic
                    unsafeAtomicAdd(&nodeacc[s0][c], ((v0 + v1) + (v2 + v3)));
                } else {
                    unsafeAtomicAdd(&nodeacc[s0][c], v0);
                    unsafeAtomicAdd(&nodeacc[s1][c], v1);
                    unsafeAtomicAdd(&nodeacc[s2][c], v2);
                    unsafeAtomicAdd(&nodeacc[s3][c], v3);
                }
            }
        };

        group(0); group(1);

        // mid-iter: gather next batch's y (nb_nxt landed under groups 0-1;
        // this gather's latency hides under groups 2-3)
        ya0 = ya1 = ya2 = 0.f;
        if (en < e_end) {
            ya0 = y[nb_nxt * 3 + 0]; ya1 = y[nb_nxt * 3 + 1]; ya2 = y[nb_nxt * 3 + 2];
        }
        nb_cur = nb_nxt;

        group(2); group(3);
    }

    __syncthreads();

    // ---- Epilogue: mean and store (each node owned by exactly this block) ----
    for (int i = t; i < nloc * (DF / 4); i += 256) {
        const int node = i >> 4;
        const int cnt  = splitsL[node + 1] - splitsL[node];
        const float inv = (cnt > 0) ? __fdividef(1.0f, (float)cnt) : 0.0f;
        float4 v = ((const float4*)nodeacc)[i];
        v.x *= inv; v.y *= inv; v.z *= inv; v.w *= inv;
        ((float4*)out)[n0 * (DF / 4) + i] = v;
    }
}

extern "C" void kernel_launch(void* const* d_in, const int* in_sizes, int n_in,
                              void* d_out, int out_size, void* d_ws, size_t ws_size,
                              hipStream_t stream) {
    const float* y   = (const float*)d_in[0];
    const float* fyv = (const float*)d_in[1];
    const float* W0  = (const float*)d_in[2];
    const float* b0  = (const float*)d_in[3];
    const float* W1  = (const float*)d_in[4];
    const float* b1  = (const float*)d_in[5];
    const int*   nb  = (const int*)d_in[6];   // harness delivers integer inputs as int32
    const int*   sp  = (const int*)d_in[7];
    it_fused<<<NBLK, 256, 0, stream>>>(y, fyv, W0, b0, W1, b1, nb, sp, (float*)d_out);
}